// Round 1
// baseline (5181.462 us; speedup 1.0000x reference)
//
#include <hip/hip_runtime.h>

#define BB 16
#define CC 32
#define KK 4
#define CKD 128     // C*K
#define NN 8192
#define NLEV 13
#define AL 128      // ALPHA (storage leading dim of weight mode axis)
#define MT 8        // modes per fwd-DFT block
#define JT 16       // j's per inv-DFT thread

struct LevTab { int off[NLEV]; int n[NLEV]; int l[NLEV]; int total; };

// tw[level_off + j*l + m] = (cos, sin)(2*pi*((j*m) mod n)/n)
__global__ void twiddle_fill_k(float2* __restrict__ tw, LevTab t) {
  int idx = blockIdx.x * blockDim.x + threadIdx.x;
  if (idx >= t.total) return;
  int lev = 0;
  for (int q = 1; q < NLEV; q++) lev = (idx >= t.off[q]) ? q : lev;
  int r = idx - t.off[lev];
  int n = t.n[lev], l = t.l[lev];
  int j = r / l, m = r - j * l;
  long long pp = ((long long)j * (long long)m) % n;
  float ang = (float)((double)pp * (6.283185307179586476925286766559 / (double)n));
  float s, c;
  sincosf(ang, &s, &c);
  tw[idx] = make_float2(c, s);
}

// x:(B,2n,C,K) -> s:(B,n,C,K), d:(B,n,C,K)
__global__ void decompose_k(const float* __restrict__ xin, float* __restrict__ sout,
                            float* __restrict__ dout,
                            const float* __restrict__ ecs, const float* __restrict__ ecd,
                            int nh) {
  int idx = blockIdx.x * blockDim.x + threadIdx.x;
  if (idx >= BB * nh * CC) return;
  int c = idx & (CC - 1);
  int t = idx / CC;
  int j = t % nh;
  int b = t / nh;
  size_t ib = (((size_t)b * (2 * nh) + 2 * j) * CC + c) * KK;
  float4 xe = *(const float4*)(xin + ib);
  float4 xo = *(const float4*)(xin + ib + CC * KK);
  float xa[8] = {xe.x, xe.y, xe.z, xe.w, xo.x, xo.y, xo.z, xo.w};
  float sv[4] = {0.f,0.f,0.f,0.f}, dv[4] = {0.f,0.f,0.f,0.f};
  #pragma unroll
  for (int p = 0; p < 8; p++) {
    float v = xa[p];
    #pragma unroll
    for (int k = 0; k < 4; k++) {
      sv[k] = fmaf(v, ecs[p*4+k], sv[k]);
      dv[k] = fmaf(v, ecd[p*4+k], dv[k]);
    }
  }
  size_t ob = (((size_t)b * nh + j) * CC + c) * KK;
  *(float4*)(sout + ob) = make_float4(sv[0], sv[1], sv[2], sv[3]);
  *(float4*)(dout + ob) = make_float4(dv[0], dv[1], dv[2], dv[3]);
}

// Xf[b,i,m] = sum_j v[b,j,i] * e^{-2pi i jm/n}, m in [0,l). Output (B,CKD,l) float2.
// blockDim=128 (lane=i). grid=(B, ceil(l/MT), 2: d/s)
__global__ void fwd_dft_k(const float* __restrict__ dsrc, const float* __restrict__ ssrc,
                          float2* __restrict__ Df, float2* __restrict__ Sf,
                          const float2* __restrict__ tw, int n, int l) {
  int i = threadIdx.x;
  int b = blockIdx.x;
  int m0 = blockIdx.y * MT;
  const float* __restrict__ src = blockIdx.z ? ssrc : dsrc;
  float2* __restrict__ dst = blockIdx.z ? Sf : Df;
  float are[MT], aim[MT];
  #pragma unroll
  for (int q = 0; q < MT; q++) { are[q] = 0.f; aim[q] = 0.f; }
  const float* __restrict__ vp = src + (size_t)b * n * CKD + i;
  const float2* __restrict__ twp = tw + m0;
  int mrem = l - m0;
  if (mrem >= MT) {
    #pragma unroll 4
    for (int j = 0; j < n; j++) {
      float v = vp[(size_t)j * CKD];
      const float2* twj = twp + (size_t)j * l;   // wave-uniform -> scalar loads
      #pragma unroll
      for (int q = 0; q < MT; q++) {
        float2 cs = twj[q];
        are[q] = fmaf(v, cs.x, are[q]);
        aim[q] = fmaf(-v, cs.y, aim[q]);
      }
    }
  } else {
    for (int j = 0; j < n; j++) {
      float v = vp[(size_t)j * CKD];
      const float2* twj = twp + (size_t)j * l;
      for (int q = 0; q < mrem; q++) {
        float2 cs = twj[q];
        are[q] = fmaf(v, cs.x, are[q]);
        aim[q] = fmaf(-v, cs.y, aim[q]);
      }
    }
  }
  #pragma unroll
  for (int q = 0; q < MT; q++) {
    if (m0 + q < l) dst[((size_t)b * CKD + i) * l + (m0 + q)] = make_float2(are[q], aim[q]);
  }
}

// Uf[b,m,o] = sum_i Df[b,i,m]*WA[i,o,m] + Sf[b,i,m]*WB[i,o,m]; Vf = Df*WC
// block=256 (m lane 0..127, o-half), grid=(64, 4: b-quads). Output (B,l,CKD) float2.
__global__ void mix_k(const float2* __restrict__ Df, const float2* __restrict__ Sf,
                      const float* __restrict__ Ar, const float* __restrict__ Ai,
                      const float* __restrict__ Br, const float* __restrict__ Bi,
                      const float* __restrict__ Cr, const float* __restrict__ Ci,
                      float2* __restrict__ Uf, float2* __restrict__ Vf, int l) {
  int m = threadIdx.x & (CKD - 1);
  int oh = threadIdx.x >> 7;
  int o = (blockIdx.x << 1) + oh;
  int b0 = blockIdx.y << 2;
  if (m >= l) return;
  float ur[4] = {0.f,0.f,0.f,0.f}, ui[4] = {0.f,0.f,0.f,0.f};
  float vr[4] = {0.f,0.f,0.f,0.f}, vi[4] = {0.f,0.f,0.f,0.f};
  for (int i = 0; i < CKD; i++) {
    size_t wb = ((size_t)i * CKD + o) * AL + m;
    float ar = Ar[wb], ai = Ai[wb];
    float br = Br[wb], bi = Bi[wb];
    float cr = Cr[wb], ci = Ci[wb];
    #pragma unroll
    for (int q = 0; q < 4; q++) {
      size_t sb = ((size_t)(b0 + q) * CKD + i) * l + m;
      float2 d = Df[sb];
      float2 s = Sf[sb];
      ur[q] += d.x*ar - d.y*ai + s.x*br - s.y*bi;
      ui[q] += d.x*ai + d.y*ar + s.x*bi + s.y*br;
      vr[q] += d.x*cr - d.y*ci;
      vi[q] += d.x*ci + d.y*cr;
    }
  }
  #pragma unroll
  for (int q = 0; q < 4; q++) {
    size_t ob = ((size_t)(b0 + q) * l + m) * CKD + o;
    Uf[ob] = make_float2(ur[q], ui[q]);
    Vf[ob] = make_float2(vr[q], vi[q]);
  }
}

// y[b,j,o] = (1/n)[ G[0].re + 2*sum_{m=1..M}(G.re cos - G.im sin) + nyq*G[l-1].re*(-1)^j ]
// blockDim=128 (lane=o). grid=(B, ceil(n/JT), 2: U/V)
__global__ void inv_dft_k(const float2* __restrict__ Uf, const float2* __restrict__ Vf,
                          float* __restrict__ ud, float* __restrict__ us,
                          const float2* __restrict__ tw, int n, int l, int nyq) {
  int o = threadIdx.x;
  int b = blockIdx.x;
  int j0 = blockIdx.y * JT;
  if (j0 >= n) return;
  const float2* __restrict__ G = (blockIdx.z ? Vf : Uf) + (size_t)b * l * CKD + o;
  float* __restrict__ out = (blockIdx.z ? us : ud) + ((size_t)b * n) * CKD + o;
  float acc[JT];
  #pragma unroll
  for (int t = 0; t < JT; t++) acc[t] = 0.f;
  float r0 = G[0].x;
  int M = l - 1;
  int hm = n / 2 - 1;
  if (M > hm) M = hm;
  for (int m = 1; m <= M; m++) {
    float2 g = G[(size_t)m * CKD];
    const float2* twm = tw + m;
    #pragma unroll
    for (int t = 0; t < JT; t++) {
      int j = j0 + t;
      if (j < n) {
        float2 cs = twm[(size_t)j * l];  // wave-uniform -> scalar load
        acc[t] += g.x*cs.x - g.y*cs.y;
      }
    }
  }
  float rn = 0.f;
  if (nyq) rn = G[(size_t)(l - 1) * CKD].x;
  float invn = 1.f / (float)n;
  #pragma unroll
  for (int t = 0; t < JT; t++) {
    int j = j0 + t;
    if (j < n) {
      float y = r0 + 2.f * acc[t];
      if (nyq) y += (j & 1) ? -rn : rn;
      out[(size_t)j * CKD] = y * invn;
    }
  }
}

// coarsest map: y = x @ T0_w^T + T0_b  over last dim K
__global__ void t0_k(const float* __restrict__ xin, const float* __restrict__ w,
                     const float* __restrict__ bv, float* __restrict__ xout) {
  int idx = blockIdx.x * blockDim.x + threadIdx.x;
  if (idx >= BB * CC * KK) return;
  int k = idx & 3;
  int bc = idx >> 2;
  float a = bv[k];
  #pragma unroll
  for (int kp = 0; kp < 4; kp++) a = fmaf(xin[bc*4 + kp], w[k*4 + kp], a);
  xout[idx] = a;
}

// x = recon(x + Us, Ud): xx=[x+Us, Ud] (8), even=xx@rc_e, odd=xx@rc_o, interleave
__global__ void recon_k(const float* __restrict__ xin, const float* __restrict__ usl,
                        const float* __restrict__ udl,
                        const float* __restrict__ rce, const float* __restrict__ rco,
                        float* __restrict__ xout, int nh) {
  int idx = blockIdx.x * blockDim.x + threadIdx.x;
  if (idx >= BB * nh * CC) return;
  int c = idx & (CC - 1);
  int t = idx / CC;
  int j = t % nh;
  int b = t / nh;
  size_t ib = (((size_t)b * nh + j) * CC + c) * KK;
  float4 xv = *(const float4*)(xin + ib);
  float4 uv = *(const float4*)(usl + ib);
  float4 dv = *(const float4*)(udl + ib);
  float xx[8] = {xv.x+uv.x, xv.y+uv.y, xv.z+uv.z, xv.w+uv.w, dv.x, dv.y, dv.z, dv.w};
  float ev[4] = {0.f,0.f,0.f,0.f}, ov[4] = {0.f,0.f,0.f,0.f};
  #pragma unroll
  for (int p = 0; p < 8; p++) {
    float v = xx[p];
    #pragma unroll
    for (int k = 0; k < 4; k++) {
      ev[k] = fmaf(v, rce[p*4+k], ev[k]);
      ov[k] = fmaf(v, rco[p*4+k], ov[k]);
    }
  }
  size_t ob = (((size_t)b * (2*nh) + 2*j) * CC + c) * KK;
  *(float4*)(xout + ob) = make_float4(ev[0], ev[1], ev[2], ev[3]);
  *(float4*)(xout + ob + CC*KK) = make_float4(ov[0], ov[1], ov[2], ov[3]);
}

extern "C" void kernel_launch(void* const* d_in, const int* in_sizes, int n_in,
                              void* d_out, int out_size, void* d_ws, size_t ws_size,
                              hipStream_t stream) {
  const float* x   = (const float*)d_in[0];
  const float* wAr = (const float*)d_in[1];
  const float* wAi = (const float*)d_in[2];
  const float* wBr = (const float*)d_in[3];
  const float* wBi = (const float*)d_in[4];
  const float* wCr = (const float*)d_in[5];
  const float* wCi = (const float*)d_in[6];
  // dict order: ec_s, ec_d, rc_e, rc_o, T0_w, T0_b. Defensive: if [7] is 16 elems it's T0_w (signature order).
  const float *ecs, *ecd, *rce, *rco, *t0w, *t0b;
  if (in_sizes[7] == 16) {
    t0w = (const float*)d_in[7];  t0b = (const float*)d_in[8];
    ecs = (const float*)d_in[9];  ecd = (const float*)d_in[10];
    rce = (const float*)d_in[11]; rco = (const float*)d_in[12];
  } else {
    ecs = (const float*)d_in[7];  ecd = (const float*)d_in[8];
    rce = (const float*)d_in[9];  rco = (const float*)d_in[10];
    t0w = (const float*)d_in[11]; t0b = (const float*)d_in[12];
  }

  int nh[NLEV], lv[NLEV];
  size_t soff[NLEV], twoff[NLEV];
  size_t sacc = 0, tacc = 0;
  for (int q = 0; q < NLEV; q++) {
    nh[q] = NN >> (q + 1);                       // skft length at this level
    int li = nh[q] / 2 + 1;
    lv[q] = li < AL ? li : AL;
    soff[q] = sacc;  sacc += (size_t)BB * nh[q] * CKD;
    twoff[q] = tacc; tacc += (size_t)nh[q] * lv[q];
  }

  float* ws = (float*)d_ws;
  const size_t XS  = (size_t)BB * (NN/2) * CKD;  // 8,388,608 floats
  const size_t SPC = (size_t)BB * CKD * AL;      // spectra, in float2 units
  float*  Ud  = ws;
  float*  Us  = Ud + sacc;
  float*  xb0 = Us + sacc;
  float*  xb1 = xb0 + XS;
  float2* Df  = (float2*)(xb1 + XS);
  float2* Sf  = Df + SPC;
  float2* Uf  = Sf + SPC;
  float2* Vf  = Uf + SPC;
  float2* tw  = Vf + SPC;

  LevTab lt;
  for (int q = 0; q < NLEV; q++) { lt.off[q] = (int)twoff[q]; lt.n[q] = nh[q]; lt.l[q] = lv[q]; }
  lt.total = (int)tacc;
  twiddle_fill_k<<<dim3((unsigned)((tacc + 255) / 256)), 256, 0, stream>>>(tw, lt);

  // ---------- decompose ----------
  const float* cur = x;
  float* nxt = xb0;
  for (int q = 0; q < NLEV; q++) {
    int n2 = nh[q], l = lv[q];
    float* dtmp = Ud + soff[q];                  // stage d in Ud slot (overwritten by iDFT)
    int tot = BB * n2 * CC;
    decompose_k<<<dim3((tot + 255) / 256), 256, 0, stream>>>(cur, nxt, dtmp, ecs, ecd, n2);
    fwd_dft_k<<<dim3(BB, (l + MT - 1) / MT, 2), 128, 0, stream>>>(dtmp, nxt, Df, Sf,
                                                                  tw + twoff[q], n2, l);
    mix_k<<<dim3(CKD / 2, BB / 4), 256, 0, stream>>>(Df, Sf, wAr, wAi, wBr, wBi, wCr, wCi,
                                                     Uf, Vf, l);
    int nyq = (((n2 & 1) == 0) && (l == n2 / 2 + 1)) ? 1 : 0;
    inv_dft_k<<<dim3(BB, (n2 + JT - 1) / JT, 2), 128, 0, stream>>>(Uf, Vf, Ud + soff[q],
                                                                   Us + soff[q],
                                                                   tw + twoff[q], n2, l, nyq);
    cur = nxt;
    nxt = (nxt == xb0) ? xb1 : xb0;
  }

  // ---------- coarsest linear map ----------
  t0_k<<<dim3((BB * CC * KK + 255) / 256), 256, 0, stream>>>(cur, t0w, t0b, nxt);

  // ---------- reconstruct ----------
  const float* rcur = nxt;
  float* rnxt = (nxt == xb0) ? xb1 : xb0;
  for (int q = NLEV - 1; q >= 0; q--) {
    int n2 = nh[q];
    float* outp = (q == 0) ? (float*)d_out : rnxt;
    int tot = BB * n2 * CC;
    recon_k<<<dim3((tot + 255) / 256), 256, 0, stream>>>(rcur, Us + soff[q], Ud + soff[q],
                                                         rce, rco, outp, n2);
    rcur = outp;
    rnxt = (rnxt == xb0) ? xb1 : xb0;
  }
}

// Round 2
// 3093.134 us; speedup vs baseline: 1.6751x; 1.6751x over previous
//
#include <hip/hip_runtime.h>

#define BB 16
#define CC 32
#define KK 4
#define CKD 128     // C*K
#define NN 8192
#define NLEV 13
#define AL 128      // ALPHA

struct LevTab { int off[NLEV]; int n[NLEV]; int l[NLEV]; int total; };

// tw [j][m] and twT [m][j]; value = (cos,sin)(2*pi*((j*m) mod n)/n)
__global__ void twiddle_fill_k(float2* __restrict__ tw, float2* __restrict__ twT, LevTab t) {
  int idx = blockIdx.x * blockDim.x + threadIdx.x;
  if (idx >= t.total) return;
  int lev = 0;
  for (int q = 1; q < NLEV; q++) lev = (idx >= t.off[q]) ? q : lev;
  int r = idx - t.off[lev];
  int n = t.n[lev], l = t.l[lev];
  int j = r / l, m = r - j * l;
  long long pp = ((long long)j * (long long)m) % n;
  float ang = (float)((double)pp * (6.283185307179586476925286766559 / (double)n));
  float s, c;
  sincosf(ang, &s, &c);
  float2 v = make_float2(c, s);
  tw[t.off[lev] + j * l + m] = v;
  twT[t.off[lev] + m * n + j] = v;
}

// x:(B,2n,C,K) -> s:(B,n,C,K), d:(B,n,C,K)
__global__ void decompose_k(const float* __restrict__ xin, float* __restrict__ sout,
                            float* __restrict__ dout,
                            const float* __restrict__ ecs, const float* __restrict__ ecd,
                            int nh) {
  int idx = blockIdx.x * blockDim.x + threadIdx.x;
  if (idx >= BB * nh * CC) return;
  int c = idx & (CC - 1);
  int t = idx / CC;
  int j = t % nh;
  int b = t / nh;
  size_t ib = (((size_t)b * (2 * nh) + 2 * j) * CC + c) * KK;
  float4 xe = *(const float4*)(xin + ib);
  float4 xo = *(const float4*)(xin + ib + CC * KK);
  float xa[8] = {xe.x, xe.y, xe.z, xe.w, xo.x, xo.y, xo.z, xo.w};
  float sv[4] = {0.f,0.f,0.f,0.f}, dv[4] = {0.f,0.f,0.f,0.f};
  #pragma unroll
  for (int p = 0; p < 8; p++) {
    float v = xa[p];
    #pragma unroll
    for (int k = 0; k < 4; k++) {
      sv[k] = fmaf(v, ecs[p*4+k], sv[k]);
      dv[k] = fmaf(v, ecd[p*4+k], dv[k]);
    }
  }
  size_t ob = (((size_t)b * nh + j) * CC + c) * KK;
  *(float4*)(sout + ob) = make_float4(sv[0], sv[1], sv[2], sv[3]);
  *(float4*)(dout + ob) = make_float4(dv[0], dv[1], dv[2], dv[3]);
}

// ---- tiled forward DFT: Xf[b,i,m] = sum_j v[b,j,i]*(cos,-sin)(jm) ----
// block 256 = 16tx(m) x 16ty(i); tile 64i x 64m(complex); K = j chunked by 16.
// grid: x = ceil(l/64), y = b*2+itile, z = src*2 + ks (K-split 2)
__global__ void fwd_dft_t(const float* __restrict__ dsrc, const float* __restrict__ ssrc,
                          float2* __restrict__ Dp, float2* __restrict__ Sp,
                          const float2* __restrict__ tw, int n, int l) {
  __shared__ float  As[16][64];
  __shared__ float2 Bs[16][64];
  int zz = blockIdx.z;
  int ks = zz & 1, srcs = zz >> 1;
  const float* __restrict__ src = srcs ? ssrc : dsrc;
  float2* __restrict__ dst = (srcs ? Sp : Dp) + (size_t)ks * BB * CKD * l;
  int m0 = blockIdx.x << 6;
  int by = blockIdx.y;
  int it = by & 1, b = by >> 1;
  int i0 = it << 6;
  int tid = threadIdx.x;
  int tx = tid & 15, ty = tid >> 4;
  int half = (n + 1) >> 1;
  int k_start = ks * half;
  int k_cnt = ks ? (n - half) : half;
  float are[4][4], aim[4][4];
  #pragma unroll
  for (int a = 0; a < 4; a++)
    #pragma unroll
    for (int d = 0; d < 4; d++) { are[a][d] = 0.f; aim[a][d] = 0.f; }

  for (int j0 = 0; j0 < k_cnt; j0 += 16) {
    { // stage A: 16 rows x 64 floats
      int row = tid >> 4;
      int c4 = (tid & 15) << 2;
      float4 v = make_float4(0.f,0.f,0.f,0.f);
      if (j0 + row < k_cnt) {
        int jg = k_start + j0 + row;
        v = *(const float4*)(src + ((size_t)b * n + jg) * CKD + i0 + c4);
      }
      *(float4*)&As[row][c4] = v;
    }
    #pragma unroll
    for (int it2 = 0; it2 < 2; it2++) { // stage B: 16 rows x 64 float2
      int idx = tid + (it2 << 8);
      int row = idx >> 5;
      int cm = (idx & 31) << 1;
      float4 v = make_float4(0.f,0.f,0.f,0.f);
      if (j0 + row < k_cnt) {
        int jg = k_start + j0 + row;
        int mg = m0 + cm;
        if (mg + 1 < l) v = *(const float4*)(tw + (size_t)jg * l + mg);
        else if (mg < l) { float2 t2 = tw[(size_t)jg * l + mg]; v.x = t2.x; v.y = t2.y; }
      }
      *(float4*)&Bs[row][cm] = v;
    }
    __syncthreads();
    #pragma unroll
    for (int j = 0; j < 16; j++) {
      float av[4];
      float2 cs[4];
      *(float4*)av = *(const float4*)&As[j][ty << 2];
      *(float4*)&cs[0] = *(const float4*)&Bs[j][tx << 2];
      *(float4*)&cs[2] = *(const float4*)&Bs[j][(tx << 2) + 2];
      #pragma unroll
      for (int ii = 0; ii < 4; ii++)
        #pragma unroll
        for (int mm = 0; mm < 4; mm++) {
          are[ii][mm] = fmaf(av[ii],  cs[mm].x, are[ii][mm]);
          aim[ii][mm] = fmaf(av[ii], -cs[mm].y, aim[ii][mm]);
        }
    }
    __syncthreads();
  }
  #pragma unroll
  for (int ii = 0; ii < 4; ii++) {
    int i = i0 + (ty << 2) + ii;
    #pragma unroll
    for (int mm = 0; mm < 4; mm++) {
      int m = m0 + (tx << 2) + mm;
      if (m < l) dst[((size_t)b * CKD + i) * l + m] = make_float2(are[ii][mm], aim[ii][mm]);
    }
  }
}

// mix: Uf[b,m,o] = sum_i (D0+D1)[b,i,m]*WA + (S0+S1)[b,i,m]*WB ; Vf = D*WC
__global__ void mix_k(const float2* __restrict__ D0, const float2* __restrict__ D1,
                      const float2* __restrict__ S0, const float2* __restrict__ S1,
                      const float* __restrict__ Ar, const float* __restrict__ Ai,
                      const float* __restrict__ Br, const float* __restrict__ Bi,
                      const float* __restrict__ Cr, const float* __restrict__ Ci,
                      float2* __restrict__ Uf, float2* __restrict__ Vf, int l) {
  int m = threadIdx.x & (CKD - 1);
  int oh = threadIdx.x >> 7;
  int o = (blockIdx.x << 1) + oh;
  int b0 = blockIdx.y << 2;
  if (m >= l) return;
  float ur[4] = {0.f,0.f,0.f,0.f}, ui[4] = {0.f,0.f,0.f,0.f};
  float vr[4] = {0.f,0.f,0.f,0.f}, vi[4] = {0.f,0.f,0.f,0.f};
  for (int i = 0; i < CKD; i++) {
    size_t wb = ((size_t)i * CKD + o) * AL + m;
    float ar = Ar[wb], ai = Ai[wb];
    float br = Br[wb], bi = Bi[wb];
    float cr = Cr[wb], ci = Ci[wb];
    #pragma unroll
    for (int q = 0; q < 4; q++) {
      size_t sb = ((size_t)(b0 + q) * CKD + i) * l + m;
      float2 da = D0[sb], db = D1[sb];
      float2 sa = S0[sb], sb2 = S1[sb];
      float dx = da.x + db.x, dy = da.y + db.y;
      float sx = sa.x + sb2.x, sy = sa.y + sb2.y;
      ur[q] += dx*ar - dy*ai + sx*br - sy*bi;
      ui[q] += dx*ai + dy*ar + sx*bi + sy*br;
      vr[q] += dx*cr - dy*ci;
      vi[q] += dx*ci + dy*cr;
    }
  }
  #pragma unroll
  for (int q = 0; q < 4; q++) {
    size_t ob = ((size_t)(b0 + q) * l + m) * CKD + o;
    Uf[ob] = make_float2(ur[q], ui[q]);
    Vf[ob] = make_float2(vr[q], vi[q]);
  }
}

// ---- tiled inverse DFT ----
// y[b,j,o] = (2*sum_{m=0..l-1}(Gr*cos - Gi*sin) - G0.re - nyq*(-1)^j*G[l-1].re)/n
// block 256 = 16tx(o) x 16ty(j); tile 64j x 64o; K = m chunked by 16.
// grid: x = ceil(n/64), y = b*2 + otile, z = 2 (U->ud, V->us)
__global__ void inv_dft_t(const float2* __restrict__ Uf, const float2* __restrict__ Vf,
                          float* __restrict__ ud, float* __restrict__ us,
                          const float2* __restrict__ twT, int n, int l, int nyq) {
  __shared__ float2 Gs[16][64];
  __shared__ float2 Ts[16][64];
  int z = blockIdx.z;
  const float2* __restrict__ G = (z ? Vf : Uf);
  float* __restrict__ out = (z ? us : ud);
  int j0 = blockIdx.x << 6;
  int by = blockIdx.y;
  int ot = by & 1, b = by >> 1;
  int o0 = ot << 6;
  int tid = threadIdx.x;
  int tx = tid & 15, ty = tid >> 4;
  float acc[4][4];
  #pragma unroll
  for (int a = 0; a < 4; a++)
    #pragma unroll
    for (int d = 0; d < 4; d++) acc[a][d] = 0.f;

  for (int m0 = 0; m0 < l; m0 += 16) {
    #pragma unroll
    for (int it2 = 0; it2 < 2; it2++) { // stage G: 16 m-rows x 64 o float2
      int idx = tid + (it2 << 8);
      int row = idx >> 5;
      int co = (idx & 31) << 1;
      float4 v = make_float4(0.f,0.f,0.f,0.f);
      if (m0 + row < l)
        v = *(const float4*)(G + ((size_t)b * l + m0 + row) * CKD + o0 + co);
      *(float4*)&Gs[row][co] = v;
    }
    #pragma unroll
    for (int it2 = 0; it2 < 2; it2++) { // stage T: 16 m-rows x 64 j float2
      int idx = tid + (it2 << 8);
      int row = idx >> 5;
      int cj = (idx & 31) << 1;
      float4 v = make_float4(0.f,0.f,0.f,0.f);
      if (m0 + row < l) {
        int jg = j0 + cj;
        if (jg + 1 < n) v = *(const float4*)(twT + (size_t)(m0 + row) * n + jg);
        else if (jg < n) { float2 t2 = twT[(size_t)(m0 + row) * n + jg]; v.x = t2.x; v.y = t2.y; }
      }
      *(float4*)&Ts[row][cj] = v;
    }
    __syncthreads();
    #pragma unroll
    for (int mm = 0; mm < 16; mm++) {
      float2 g[4], cs[4];
      *(float4*)&g[0]  = *(const float4*)&Gs[mm][tx << 2];
      *(float4*)&g[2]  = *(const float4*)&Gs[mm][(tx << 2) + 2];
      *(float4*)&cs[0] = *(const float4*)&Ts[mm][ty << 2];
      *(float4*)&cs[2] = *(const float4*)&Ts[mm][(ty << 2) + 2];
      #pragma unroll
      for (int jj = 0; jj < 4; jj++)
        #pragma unroll
        for (int oo = 0; oo < 4; oo++) {
          acc[jj][oo] = fmaf(g[oo].x,  cs[jj].x, acc[jj][oo]);
          acc[jj][oo] = fmaf(g[oo].y, -cs[jj].y, acc[jj][oo]);
        }
    }
    __syncthreads();
  }
  float invn = 1.f / (float)n;
  float g0[4], gn[4];
  #pragma unroll
  for (int oo = 0; oo < 4; oo++) {
    int o = o0 + (tx << 2) + oo;
    g0[oo] = G[((size_t)b * l) * CKD + o].x;
    gn[oo] = nyq ? G[((size_t)b * l + (l - 1)) * CKD + o].x : 0.f;
  }
  #pragma unroll
  for (int jj = 0; jj < 4; jj++) {
    int j = j0 + (ty << 2) + jj;
    if (j < n) {
      float sgn = (j & 1) ? -1.f : 1.f;
      float4 y;
      float* yp = &y.x;
      #pragma unroll
      for (int oo = 0; oo < 4; oo++)
        yp[oo] = (2.f * acc[jj][oo] - g0[oo] - sgn * gn[oo]) * invn;
      *(float4*)(out + ((size_t)b * n + j) * CKD + o0 + (tx << 2)) = y;
    }
  }
}

// coarsest map: y = x @ T0_w^T + T0_b
__global__ void t0_k(const float* __restrict__ xin, const float* __restrict__ w,
                     const float* __restrict__ bv, float* __restrict__ xout) {
  int idx = blockIdx.x * blockDim.x + threadIdx.x;
  if (idx >= BB * CC * KK) return;
  int k = idx & 3;
  int bc = idx >> 2;
  float a = bv[k];
  #pragma unroll
  for (int kp = 0; kp < 4; kp++) a = fmaf(xin[bc*4 + kp], w[k*4 + kp], a);
  xout[idx] = a;
}

__global__ void recon_k(const float* __restrict__ xin, const float* __restrict__ usl,
                        const float* __restrict__ udl,
                        const float* __restrict__ rce, const float* __restrict__ rco,
                        float* __restrict__ xout, int nh) {
  int idx = blockIdx.x * blockDim.x + threadIdx.x;
  if (idx >= BB * nh * CC) return;
  int c = idx & (CC - 1);
  int t = idx / CC;
  int j = t % nh;
  int b = t / nh;
  size_t ib = (((size_t)b * nh + j) * CC + c) * KK;
  float4 xv = *(const float4*)(xin + ib);
  float4 uv = *(const float4*)(usl + ib);
  float4 dv = *(const float4*)(udl + ib);
  float xx[8] = {xv.x+uv.x, xv.y+uv.y, xv.z+uv.z, xv.w+uv.w, dv.x, dv.y, dv.z, dv.w};
  float ev[4] = {0.f,0.f,0.f,0.f}, ov[4] = {0.f,0.f,0.f,0.f};
  #pragma unroll
  for (int p = 0; p < 8; p++) {
    float v = xx[p];
    #pragma unroll
    for (int k = 0; k < 4; k++) {
      ev[k] = fmaf(v, rce[p*4+k], ev[k]);
      ov[k] = fmaf(v, rco[p*4+k], ov[k]);
    }
  }
  size_t ob = (((size_t)b * (2*nh) + 2*j) * CC + c) * KK;
  *(float4*)(xout + ob) = make_float4(ev[0], ev[1], ev[2], ev[3]);
  *(float4*)(xout + ob + CC*KK) = make_float4(ov[0], ov[1], ov[2], ov[3]);
}

extern "C" void kernel_launch(void* const* d_in, const int* in_sizes, int n_in,
                              void* d_out, int out_size, void* d_ws, size_t ws_size,
                              hipStream_t stream) {
  const float* x   = (const float*)d_in[0];
  const float* wAr = (const float*)d_in[1];
  const float* wAi = (const float*)d_in[2];
  const float* wBr = (const float*)d_in[3];
  const float* wBi = (const float*)d_in[4];
  const float* wCr = (const float*)d_in[5];
  const float* wCi = (const float*)d_in[6];
  const float *ecs, *ecd, *rce, *rco, *t0w, *t0b;
  if (in_sizes[7] == 16) {
    t0w = (const float*)d_in[7];  t0b = (const float*)d_in[8];
    ecs = (const float*)d_in[9];  ecd = (const float*)d_in[10];
    rce = (const float*)d_in[11]; rco = (const float*)d_in[12];
  } else {
    ecs = (const float*)d_in[7];  ecd = (const float*)d_in[8];
    rce = (const float*)d_in[9];  rco = (const float*)d_in[10];
    t0w = (const float*)d_in[11]; t0b = (const float*)d_in[12];
  }

  int nh[NLEV], lv[NLEV];
  size_t soff[NLEV], twoff[NLEV];
  size_t sacc = 0, tacc = 0;
  for (int q = 0; q < NLEV; q++) {
    nh[q] = NN >> (q + 1);
    int li = nh[q] / 2 + 1;
    lv[q] = li < AL ? li : AL;
    soff[q] = sacc;  sacc += (size_t)BB * nh[q] * CKD;
    twoff[q] = tacc; tacc += (size_t)nh[q] * lv[q];
  }

  float* ws = (float*)d_ws;
  const size_t XS  = (size_t)BB * (NN/2) * CKD;
  const size_t SPC = (size_t)BB * CKD * AL;      // float2 units
  float*  Ud  = ws;
  float*  Us  = Ud + sacc;
  float*  xb0 = Us + sacc;
  float*  xb1 = xb0 + XS;
  float2* Df  = (float2*)(xb1 + XS);   // 2 partials
  float2* Sf  = Df + 2 * SPC;          // 2 partials
  float2* Uf  = Sf + 2 * SPC;
  float2* Vf  = Uf + SPC;
  float2* tw  = Vf + SPC;
  float2* twT = tw + tacc;

  LevTab lt;
  for (int q = 0; q < NLEV; q++) { lt.off[q] = (int)twoff[q]; lt.n[q] = nh[q]; lt.l[q] = lv[q]; }
  lt.total = (int)tacc;
  twiddle_fill_k<<<dim3((unsigned)((tacc + 255) / 256)), 256, 0, stream>>>(tw, twT, lt);

  // ---------- decompose ----------
  const float* cur = x;
  float* nxt = xb0;
  for (int q = 0; q < NLEV; q++) {
    int n2 = nh[q], l = lv[q];
    float* dtmp = Ud + soff[q];   // stage d in Ud slot
    int tot = BB * n2 * CC;
    decompose_k<<<dim3((tot + 255) / 256), 256, 0, stream>>>(cur, nxt, dtmp, ecs, ecd, n2);
    fwd_dft_t<<<dim3((l + 63) / 64, BB * 2, 4), 256, 0, stream>>>(dtmp, nxt, Df, Sf,
                                                                  tw + twoff[q], n2, l);
    size_t pstride = (size_t)BB * CKD * l;
    mix_k<<<dim3(CKD / 2, BB / 4), 256, 0, stream>>>(Df, Df + pstride, Sf, Sf + pstride,
                                                     wAr, wAi, wBr, wBi, wCr, wCi,
                                                     Uf, Vf, l);
    int nyq = (((n2 & 1) == 0) && (l == n2 / 2 + 1)) ? 1 : 0;
    inv_dft_t<<<dim3((n2 + 63) / 64, BB * 2, 2), 256, 0, stream>>>(Uf, Vf, Ud + soff[q],
                                                                   Us + soff[q],
                                                                   twT + twoff[q], n2, l, nyq);
    cur = nxt;
    nxt = (nxt == xb0) ? xb1 : xb0;
  }

  // ---------- coarsest linear map ----------
  t0_k<<<dim3((BB * CC * KK + 255) / 256), 256, 0, stream>>>(cur, t0w, t0b, nxt);

  // ---------- reconstruct ----------
  const float* rcur = nxt;
  float* rnxt = (nxt == xb0) ? xb1 : xb0;
  for (int q = NLEV - 1; q >= 0; q--) {
    int n2 = nh[q];
    float* outp = (q == 0) ? (float*)d_out : rnxt;
    int tot = BB * n2 * CC;
    recon_k<<<dim3((tot + 255) / 256), 256, 0, stream>>>(rcur, Us + soff[q], Ud + soff[q],
                                                         rce, rco, outp, n2);
    rcur = outp;
    rnxt = (rnxt == xb0) ? xb1 : xb0;
  }
}

// Round 3
// 2255.100 us; speedup vs baseline: 2.2977x; 1.3716x over previous
//
#include <hip/hip_runtime.h>

#define BB 16
#define CC 32
#define KK 4
#define CKD 128     // C*K
#define NN 8192
#define NLEV 13
#define AL 128      // ALPHA
#define PMAX 6      // max K-split for fwd DFT

struct LevTab { int off[NLEV]; int n[NLEV]; int l[NLEV]; int total; };

// tw [j][m] and twT [m][j]; value = (cos,sin)(2*pi*((j*m) mod n)/n)
__global__ void twiddle_fill_k(float2* __restrict__ tw, float2* __restrict__ twT, LevTab t) {
  int idx = blockIdx.x * blockDim.x + threadIdx.x;
  if (idx >= t.total) return;
  int lev = 0;
  for (int q = 1; q < NLEV; q++) lev = (idx >= t.off[q]) ? q : lev;
  int r = idx - t.off[lev];
  int n = t.n[lev], l = t.l[lev];
  int j = r / l, m = r - j * l;
  long long pp = ((long long)j * (long long)m) % n;
  float ang = (float)((double)pp * (6.283185307179586476925286766559 / (double)n));
  float s, c;
  sincosf(ang, &s, &c);
  float2 v = make_float2(c, s);
  tw[t.off[lev] + j * l + m] = v;
  twT[t.off[lev] + m * n + j] = v;
}

// x:(B,2n,C,K) -> s:(B,n,C,K), d:(B,n,C,K)
__global__ void decompose_k(const float* __restrict__ xin, float* __restrict__ sout,
                            float* __restrict__ dout,
                            const float* __restrict__ ecs, const float* __restrict__ ecd,
                            int nh) {
  int idx = blockIdx.x * blockDim.x + threadIdx.x;
  if (idx >= BB * nh * CC) return;
  int c = idx & (CC - 1);
  int t = idx / CC;
  int j = t % nh;
  int b = t / nh;
  size_t ib = (((size_t)b * (2 * nh) + 2 * j) * CC + c) * KK;
  float4 xe = *(const float4*)(xin + ib);
  float4 xo = *(const float4*)(xin + ib + CC * KK);
  float xa[8] = {xe.x, xe.y, xe.z, xe.w, xo.x, xo.y, xo.z, xo.w};
  float sv[4] = {0.f,0.f,0.f,0.f}, dv[4] = {0.f,0.f,0.f,0.f};
  #pragma unroll
  for (int p = 0; p < 8; p++) {
    float v = xa[p];
    #pragma unroll
    for (int k = 0; k < 4; k++) {
      sv[k] = fmaf(v, ecs[p*4+k], sv[k]);
      dv[k] = fmaf(v, ecd[p*4+k], dv[k]);
    }
  }
  size_t ob = (((size_t)b * nh + j) * CC + c) * KK;
  *(float4*)(sout + ob) = make_float4(sv[0], sv[1], sv[2], sv[3]);
  *(float4*)(dout + ob) = make_float4(dv[0], dv[1], dv[2], dv[3]);
}

// ---- tiled forward DFT: Xf[b,i,m] = sum_j v[b,j,i]*(cos,-sin)(jm) ----
// block 256 = 16tx(m) x 16ty(i); tile 64i x 64m; K = j chunked 16, split P ways.
// grid: x = ceil(l/64), y = b*2+itile, z = srcs*P + ks
__global__ void fwd_dft_t(const float* __restrict__ dsrc, const float* __restrict__ ssrc,
                          float2* __restrict__ Dp, float2* __restrict__ Sp,
                          const float2* __restrict__ tw, int n, int l, int P, int chunk) {
  __shared__ float As[16][64];
  __shared__ float Bc[16][64];
  __shared__ float Bn[16][64];
  int zz = blockIdx.z;
  int srcs = (zz >= P) ? 1 : 0;
  int ks = zz - srcs * P;
  const float* __restrict__ src = srcs ? ssrc : dsrc;
  size_t spcl = (size_t)BB * CKD * l;
  float2* __restrict__ dst = (srcs ? Sp : Dp) + (size_t)ks * spcl;
  int m0 = blockIdx.x << 6;
  int by = blockIdx.y;
  int it = by & 1, b = by >> 1;
  int i0 = it << 6;
  int tid = threadIdx.x;
  int tx = tid & 15, ty = tid >> 4;
  int k_start = ks * chunk;
  int k_cnt = n - k_start;
  if (k_cnt > chunk) k_cnt = chunk;
  float are[4][4], aim[4][4];
  #pragma unroll
  for (int a = 0; a < 4; a++)
    #pragma unroll
    for (int d = 0; d < 4; d++) { are[a][d] = 0.f; aim[a][d] = 0.f; }

  for (int j0 = 0; j0 < k_cnt; j0 += 16) {
    { // stage A: 16 j-rows x 64 i floats
      int row = tid >> 4;
      int c4 = (tid & 15) << 2;
      float4 v = make_float4(0.f,0.f,0.f,0.f);
      if (j0 + row < k_cnt) {
        int jg = k_start + j0 + row;
        v = *(const float4*)(src + ((size_t)b * n + jg) * CKD + i0 + c4);
      }
      *(float4*)&As[row][c4] = v;
    }
    #pragma unroll
    for (int it2 = 0; it2 < 2; it2++) { // stage twiddles into cos/sin planes
      int idx = tid + (it2 << 8);
      int row = idx >> 5;
      int cm = (idx & 31) << 1;
      float4 v = make_float4(0.f,0.f,0.f,0.f);
      if (j0 + row < k_cnt) {
        int jg = k_start + j0 + row;
        int mg = m0 + cm;
        if (mg + 1 < l) v = *(const float4*)(tw + (size_t)jg * l + mg);
        else if (mg < l) { float2 t2 = tw[(size_t)jg * l + mg]; v.x = t2.x; v.y = t2.y; }
      }
      Bc[row][cm] = v.x;  Bn[row][cm] = v.y;
      Bc[row][cm+1] = v.z; Bn[row][cm+1] = v.w;
    }
    __syncthreads();
    #pragma unroll
    for (int j = 0; j < 16; j++) {
      float av[4], cr[4], ci[4];
      *(float4*)av = *(const float4*)&As[j][ty << 2];
      *(float4*)cr = *(const float4*)&Bc[j][tx << 2];
      *(float4*)ci = *(const float4*)&Bn[j][tx << 2];
      #pragma unroll
      for (int ii = 0; ii < 4; ii++)
        #pragma unroll
        for (int mm = 0; mm < 4; mm++) {
          are[ii][mm] = fmaf(av[ii],  cr[mm], are[ii][mm]);
          aim[ii][mm] = fmaf(av[ii], -ci[mm], aim[ii][mm]);
        }
    }
    __syncthreads();
  }
  #pragma unroll
  for (int ii = 0; ii < 4; ii++) {
    int i = i0 + (ty << 2) + ii;
    #pragma unroll
    for (int mm = 0; mm < 4; mm++) {
      int m = m0 + (tx << 2) + mm;
      if (m < l) dst[((size_t)b * CKD + i) * l + m] = make_float2(are[ii][mm], aim[ii][mm]);
    }
  }
}

// sum P partial spectra into partial 0 (in place), element-wise float4
__global__ void reduce_k(float4* __restrict__ Df, float4* __restrict__ Sf, int cnt4, int P) {
  int idx = blockIdx.x * blockDim.x + threadIdx.x;
  if (idx >= 2 * cnt4) return;
  float4* base = (idx < cnt4) ? Df : Sf;
  int e = (idx < cnt4) ? idx : idx - cnt4;
  float4 a = base[e];
  for (int p = 1; p < P; p++) {
    float4 v = base[(size_t)p * cnt4 + e];
    a.x += v.x; a.y += v.y; a.z += v.z; a.w += v.w;
  }
  base[e] = a;
}

// mix: Uf[b,m,o] = sum_i Df[b,i,m]*WA + Sf[b,i,m]*WB ; Vf = Df*WC
__global__ void mix_k(const float2* __restrict__ Df, const float2* __restrict__ Sf,
                      const float* __restrict__ Ar, const float* __restrict__ Ai,
                      const float* __restrict__ Br, const float* __restrict__ Bi,
                      const float* __restrict__ Cr, const float* __restrict__ Ci,
                      float2* __restrict__ Uf, float2* __restrict__ Vf, int l) {
  int m = threadIdx.x & (CKD - 1);
  int oh = threadIdx.x >> 7;
  int o = (blockIdx.x << 1) + oh;
  int b0 = blockIdx.y << 2;
  if (m >= l) return;
  float ur[4] = {0.f,0.f,0.f,0.f}, ui[4] = {0.f,0.f,0.f,0.f};
  float vr[4] = {0.f,0.f,0.f,0.f}, vi[4] = {0.f,0.f,0.f,0.f};
  for (int i = 0; i < CKD; i++) {
    size_t wb = ((size_t)i * CKD + o) * AL + m;
    float ar = Ar[wb], ai = Ai[wb];
    float br = Br[wb], bi = Bi[wb];
    float cr = Cr[wb], ci = Ci[wb];
    #pragma unroll
    for (int q = 0; q < 4; q++) {
      size_t sb = ((size_t)(b0 + q) * CKD + i) * l + m;
      float2 d = Df[sb];
      float2 s = Sf[sb];
      ur[q] += d.x*ar - d.y*ai + s.x*br - s.y*bi;
      ui[q] += d.x*ai + d.y*ar + s.x*bi + s.y*br;
      vr[q] += d.x*cr - d.y*ci;
      vi[q] += d.x*ci + d.y*cr;
    }
  }
  #pragma unroll
  for (int q = 0; q < 4; q++) {
    size_t ob = ((size_t)(b0 + q) * l + m) * CKD + o;
    Uf[ob] = make_float2(ur[q], ui[q]);
    Vf[ob] = make_float2(vr[q], vi[q]);
  }
}

// ---- tiled inverse DFT ----
// y[b,j,o] = (2*sum_{m=0..l-1}(Gr*cos - Gi*sin) - G0.re - nyq*(-1)^j*G[l-1].re)/n
// block 256 = 16tx(o) x 16ty(j); tile 64j x 64o; K = m chunked by 16.
__global__ void inv_dft_t(const float2* __restrict__ Uf, const float2* __restrict__ Vf,
                          float* __restrict__ ud, float* __restrict__ us,
                          const float2* __restrict__ twT, int n, int l, int nyq) {
  __shared__ float Gr[16][64];
  __shared__ float Gi[16][64];
  __shared__ float2 Ts[16][64];
  int z = blockIdx.z;
  const float2* __restrict__ G = (z ? Vf : Uf);
  float* __restrict__ out = (z ? us : ud);
  int j0 = blockIdx.x << 6;
  int by = blockIdx.y;
  int ot = by & 1, b = by >> 1;
  int o0 = ot << 6;
  int tid = threadIdx.x;
  int tx = tid & 15, ty = tid >> 4;
  float acc[4][4];
  #pragma unroll
  for (int a = 0; a < 4; a++)
    #pragma unroll
    for (int d = 0; d < 4; d++) acc[a][d] = 0.f;

  for (int m0 = 0; m0 < l; m0 += 16) {
    #pragma unroll
    for (int it2 = 0; it2 < 2; it2++) { // stage G into re/im planes
      int idx = tid + (it2 << 8);
      int row = idx >> 5;
      int co = (idx & 31) << 1;
      float4 v = make_float4(0.f,0.f,0.f,0.f);
      if (m0 + row < l)
        v = *(const float4*)(G + ((size_t)b * l + m0 + row) * CKD + o0 + co);
      Gr[row][co] = v.x;   Gi[row][co] = v.y;
      Gr[row][co+1] = v.z; Gi[row][co+1] = v.w;
    }
    #pragma unroll
    for (int it2 = 0; it2 < 2; it2++) { // stage twT tile
      int idx = tid + (it2 << 8);
      int row = idx >> 5;
      int cj = (idx & 31) << 1;
      float4 v = make_float4(0.f,0.f,0.f,0.f);
      if (m0 + row < l) {
        int jg = j0 + cj;
        if (jg + 1 < n) v = *(const float4*)(twT + (size_t)(m0 + row) * n + jg);
        else if (jg < n) { float2 t2 = twT[(size_t)(m0 + row) * n + jg]; v.x = t2.x; v.y = t2.y; }
      }
      *(float4*)&Ts[row][cj] = v;
    }
    __syncthreads();
    #pragma unroll
    for (int mm = 0; mm < 16; mm++) {
      float gr[4], gi[4];
      float2 cs[4];
      *(float4*)gr = *(const float4*)&Gr[mm][tx << 2];
      *(float4*)gi = *(const float4*)&Gi[mm][tx << 2];
      *(float4*)&cs[0] = *(const float4*)&Ts[mm][ty << 2];
      *(float4*)&cs[2] = *(const float4*)&Ts[mm][(ty << 2) + 2];
      #pragma unroll
      for (int jj = 0; jj < 4; jj++)
        #pragma unroll
        for (int oo = 0; oo < 4; oo++) {
          acc[jj][oo] = fmaf(gr[oo],  cs[jj].x, acc[jj][oo]);
          acc[jj][oo] = fmaf(gi[oo], -cs[jj].y, acc[jj][oo]);
        }
    }
    __syncthreads();
  }
  float invn = 1.f / (float)n;
  float g0[4], gn[4];
  #pragma unroll
  for (int oo = 0; oo < 4; oo++) {
    int o = o0 + (tx << 2) + oo;
    g0[oo] = G[((size_t)b * l) * CKD + o].x;
    gn[oo] = nyq ? G[((size_t)b * l + (l - 1)) * CKD + o].x : 0.f;
  }
  #pragma unroll
  for (int jj = 0; jj < 4; jj++) {
    int j = j0 + (ty << 2) + jj;
    if (j < n) {
      float sgn = (j & 1) ? -1.f : 1.f;
      float4 y;
      float* yp = &y.x;
      #pragma unroll
      for (int oo = 0; oo < 4; oo++)
        yp[oo] = (2.f * acc[jj][oo] - g0[oo] - sgn * gn[oo]) * invn;
      *(float4*)(out + ((size_t)b * n + j) * CKD + o0 + (tx << 2)) = y;
    }
  }
}

// coarsest map: y = x @ T0_w^T + T0_b
__global__ void t0_k(const float* __restrict__ xin, const float* __restrict__ w,
                     const float* __restrict__ bv, float* __restrict__ xout) {
  int idx = blockIdx.x * blockDim.x + threadIdx.x;
  if (idx >= BB * CC * KK) return;
  int k = idx & 3;
  int bc = idx >> 2;
  float a = bv[k];
  #pragma unroll
  for (int kp = 0; kp < 4; kp++) a = fmaf(xin[bc*4 + kp], w[k*4 + kp], a);
  xout[idx] = a;
}

__global__ void recon_k(const float* __restrict__ xin, const float* __restrict__ usl,
                        const float* __restrict__ udl,
                        const float* __restrict__ rce, const float* __restrict__ rco,
                        float* __restrict__ xout, int nh) {
  int idx = blockIdx.x * blockDim.x + threadIdx.x;
  if (idx >= BB * nh * CC) return;
  int c = idx & (CC - 1);
  int t = idx / CC;
  int j = t % nh;
  int b = t / nh;
  size_t ib = (((size_t)b * nh + j) * CC + c) * KK;
  float4 xv = *(const float4*)(xin + ib);
  float4 uv = *(const float4*)(usl + ib);
  float4 dv = *(const float4*)(udl + ib);
  float xx[8] = {xv.x+uv.x, xv.y+uv.y, xv.z+uv.z, xv.w+uv.w, dv.x, dv.y, dv.z, dv.w};
  float ev[4] = {0.f,0.f,0.f,0.f}, ov[4] = {0.f,0.f,0.f,0.f};
  #pragma unroll
  for (int p = 0; p < 8; p++) {
    float v = xx[p];
    #pragma unroll
    for (int k = 0; k < 4; k++) {
      ev[k] = fmaf(v, rce[p*4+k], ev[k]);
      ov[k] = fmaf(v, rco[p*4+k], ov[k]);
    }
  }
  size_t ob = (((size_t)b * (2*nh) + 2*j) * CC + c) * KK;
  *(float4*)(xout + ob) = make_float4(ev[0], ev[1], ev[2], ev[3]);
  *(float4*)(xout + ob + CC*KK) = make_float4(ov[0], ov[1], ov[2], ov[3]);
}

extern "C" void kernel_launch(void* const* d_in, const int* in_sizes, int n_in,
                              void* d_out, int out_size, void* d_ws, size_t ws_size,
                              hipStream_t stream) {
  const float* x   = (const float*)d_in[0];
  const float* wAr = (const float*)d_in[1];
  const float* wAi = (const float*)d_in[2];
  const float* wBr = (const float*)d_in[3];
  const float* wBi = (const float*)d_in[4];
  const float* wCr = (const float*)d_in[5];
  const float* wCi = (const float*)d_in[6];
  const float *ecs, *ecd, *rce, *rco, *t0w, *t0b;
  if (in_sizes[7] == 16) {
    t0w = (const float*)d_in[7];  t0b = (const float*)d_in[8];
    ecs = (const float*)d_in[9];  ecd = (const float*)d_in[10];
    rce = (const float*)d_in[11]; rco = (const float*)d_in[12];
  } else {
    ecs = (const float*)d_in[7];  ecd = (const float*)d_in[8];
    rce = (const float*)d_in[9];  rco = (const float*)d_in[10];
    t0w = (const float*)d_in[11]; t0b = (const float*)d_in[12];
  }

  int nh[NLEV], lv[NLEV];
  size_t soff[NLEV], twoff[NLEV];
  size_t sacc = 0, tacc = 0;
  for (int q = 0; q < NLEV; q++) {
    nh[q] = NN >> (q + 1);
    int li = nh[q] / 2 + 1;
    lv[q] = li < AL ? li : AL;
    soff[q] = sacc;  sacc += (size_t)BB * nh[q] * CKD;
    twoff[q] = tacc; tacc += (size_t)nh[q] * lv[q];
  }

  float* ws = (float*)d_ws;
  const size_t XS  = (size_t)BB * (NN/2) * CKD;
  const size_t SPC = (size_t)BB * CKD * AL;      // float2 units
  float*  Ud  = ws;
  float*  Us  = Ud + sacc;
  float*  xb0 = Us + sacc;
  float*  xb1 = xb0 + XS;            // only XS/2 needed
  float2* Df  = (float2*)(xb1 + XS / 2);   // PMAX partials
  float2* Sf  = Df + PMAX * SPC;
  float2* Uf  = Sf + PMAX * SPC;
  float2* Vf  = Uf + SPC;
  float2* tw  = Vf + SPC;
  float2* twT = tw + tacc;

  LevTab lt;
  for (int q = 0; q < NLEV; q++) { lt.off[q] = (int)twoff[q]; lt.n[q] = nh[q]; lt.l[q] = lv[q]; }
  lt.total = (int)tacc;
  twiddle_fill_k<<<dim3((unsigned)((tacc + 255) / 256)), 256, 0, stream>>>(tw, twT, lt);

  // ---------- decompose ----------
  const float* cur = x;
  float* nxt = xb0;
  for (int q = 0; q < NLEV; q++) {
    int n2 = nh[q], l = lv[q];
    float* dtmp = Ud + soff[q];   // stage d in Ud slot
    int tot = BB * n2 * CC;
    decompose_k<<<dim3((tot + 255) / 256), 256, 0, stream>>>(cur, nxt, dtmp, ecs, ecd, n2);

    int P = n2 / 128; if (P < 1) P = 1; if (P > PMAX) P = PMAX;
    int chunk = (((n2 + P - 1) / P) + 15) & ~15;
    fwd_dft_t<<<dim3((l + 63) / 64, BB * 2, 2 * P), 256, 0, stream>>>(dtmp, nxt, Df, Sf,
                                                                      tw + twoff[q], n2, l,
                                                                      P, chunk);
    if (P > 1) {
      int cnt4 = (BB * CKD * l) / 2;   // float4 count per partial (l*16*128*2 floats /4)
      reduce_k<<<dim3((2 * cnt4 + 255) / 256), 256, 0, stream>>>((float4*)Df, (float4*)Sf,
                                                                 cnt4, P);
    }
    mix_k<<<dim3(CKD / 2, BB / 4), 256, 0, stream>>>(Df, Sf, wAr, wAi, wBr, wBi, wCr, wCi,
                                                     Uf, Vf, l);
    int nyq = (((n2 & 1) == 0) && (l == n2 / 2 + 1)) ? 1 : 0;
    inv_dft_t<<<dim3((n2 + 63) / 64, BB * 2, 2), 256, 0, stream>>>(Uf, Vf, Ud + soff[q],
                                                                   Us + soff[q],
                                                                   twT + twoff[q], n2, l, nyq);
    cur = nxt;
    nxt = (nxt == xb0) ? xb1 : xb0;
  }

  // ---------- coarsest linear map ----------
  t0_k<<<dim3((BB * CC * KK + 255) / 256), 256, 0, stream>>>(cur, t0w, t0b, nxt);

  // ---------- reconstruct ----------
  const float* rcur = nxt;
  float* rnxt = (nxt == xb0) ? xb1 : xb0;
  for (int q = NLEV - 1; q >= 0; q--) {
    int n2 = nh[q];
    float* outp = (q == 0) ? (float*)d_out : rnxt;
    int tot = BB * n2 * CC;
    recon_k<<<dim3((tot + 255) / 256), 256, 0, stream>>>(rcur, Us + soff[q], Ud + soff[q],
                                                         rce, rco, outp, n2);
    rcur = outp;
    rnxt = (rnxt == xb0) ? xb1 : xb0;
  }
}

// Round 4
// 1414.315 us; speedup vs baseline: 3.6636x; 1.5945x over previous
//
#include <hip/hip_runtime.h>

#define BB 16
#define CC 32
#define KK 4
#define CKD 128     // C*K
#define NN 8192
#define NLEV 13
#define AL 128      // ALPHA (weight mode-axis storage stride)
#define PMAX 6      // max K-split for fwd DFT

struct LevTab { int off[NLEV]; int n[NLEV]; int l[NLEV]; int total; };
struct MixTab { long long off[NLEV]; int l[NLEV]; };

// tw [j][m] and twT [m][j]; value = (cos,sin)(2*pi*((j*m) mod n)/n)
__global__ void twiddle_fill_k(float2* __restrict__ tw, float2* __restrict__ twT, LevTab t) {
  int idx = blockIdx.x * blockDim.x + threadIdx.x;
  if (idx >= t.total) return;
  int lev = 0;
  for (int q = 1; q < NLEV; q++) lev = (idx >= t.off[q]) ? q : lev;
  int r = idx - t.off[lev];
  int n = t.n[lev], l = t.l[lev];
  int j = r / l, m = r - j * l;
  long long pp = ((long long)j * (long long)m) % n;
  float ang = (float)((double)pp * (6.283185307179586476925286766559 / (double)n));
  float s, c;
  sincosf(ang, &s, &c);
  float2 v = make_float2(c, s);
  tw[t.off[lev] + j * l + m] = v;
  twT[t.off[lev] + m * n + j] = v;
}

// x:(B,2n,C,K) -> s:(B,n,C,K), d:(B,n,C,K)
__global__ void decompose_k(const float* __restrict__ xin, float* __restrict__ sout,
                            float* __restrict__ dout,
                            const float* __restrict__ ecs, const float* __restrict__ ecd,
                            int nh) {
  int idx = blockIdx.x * blockDim.x + threadIdx.x;
  if (idx >= BB * nh * CC) return;
  int c = idx & (CC - 1);
  int t = idx / CC;
  int j = t % nh;
  int b = t / nh;
  size_t ib = (((size_t)b * (2 * nh) + 2 * j) * CC + c) * KK;
  float4 xe = *(const float4*)(xin + ib);
  float4 xo = *(const float4*)(xin + ib + CC * KK);
  float xa[8] = {xe.x, xe.y, xe.z, xe.w, xo.x, xo.y, xo.z, xo.w};
  float sv[4] = {0.f,0.f,0.f,0.f}, dv[4] = {0.f,0.f,0.f,0.f};
  #pragma unroll
  for (int p = 0; p < 8; p++) {
    float v = xa[p];
    #pragma unroll
    for (int k = 0; k < 4; k++) {
      sv[k] = fmaf(v, ecs[p*4+k], sv[k]);
      dv[k] = fmaf(v, ecd[p*4+k], dv[k]);
    }
  }
  size_t ob = (((size_t)b * nh + j) * CC + c) * KK;
  *(float4*)(sout + ob) = make_float4(sv[0], sv[1], sv[2], sv[3]);
  *(float4*)(dout + ob) = make_float4(dv[0], dv[1], dv[2], dv[3]);
}

// ---- tiled forward DFT: Xf[b,i,m] = sum_j v[b,j,i]*(cos,-sin)(jm) ----
// block 256 = 16tx(m) x 16ty(i); tile 64i x 64m; K = j chunked 16, split P ways.
// grid: x = ceil(l/64), y = b*2+itile, z = srcs*P + ks
__global__ void fwd_dft_t(const float* __restrict__ dsrc, const float* __restrict__ ssrc,
                          float2* __restrict__ Dp, float2* __restrict__ Sp,
                          const float2* __restrict__ tw, int n, int l, int P, int chunk) {
  __shared__ float As[16][64];
  __shared__ float Bc[16][64];
  __shared__ float Bn[16][64];
  int zz = blockIdx.z;
  int srcs = (zz >= P) ? 1 : 0;
  int ks = zz - srcs * P;
  const float* __restrict__ src = srcs ? ssrc : dsrc;
  size_t spcl = (size_t)BB * CKD * l;
  float2* __restrict__ dst = (srcs ? Sp : Dp) + (size_t)ks * spcl;
  int m0 = blockIdx.x << 6;
  int by = blockIdx.y;
  int it = by & 1, b = by >> 1;
  int i0 = it << 6;
  int tid = threadIdx.x;
  int tx = tid & 15, ty = tid >> 4;
  int k_start = ks * chunk;
  int k_cnt = n - k_start;
  if (k_cnt > chunk) k_cnt = chunk;
  float are[4][4], aim[4][4];
  #pragma unroll
  for (int a = 0; a < 4; a++)
    #pragma unroll
    for (int d = 0; d < 4; d++) { are[a][d] = 0.f; aim[a][d] = 0.f; }

  for (int j0 = 0; j0 < k_cnt; j0 += 16) {
    { // stage A: 16 j-rows x 64 i floats
      int row = tid >> 4;
      int c4 = (tid & 15) << 2;
      float4 v = make_float4(0.f,0.f,0.f,0.f);
      if (j0 + row < k_cnt) {
        int jg = k_start + j0 + row;
        v = *(const float4*)(src + ((size_t)b * n + jg) * CKD + i0 + c4);
      }
      *(float4*)&As[row][c4] = v;
    }
    #pragma unroll
    for (int it2 = 0; it2 < 2; it2++) { // stage twiddles into cos/sin planes
      int idx = tid + (it2 << 8);
      int row = idx >> 5;
      int cm = (idx & 31) << 1;
      float4 v = make_float4(0.f,0.f,0.f,0.f);
      if (j0 + row < k_cnt) {
        int jg = k_start + j0 + row;
        int mg = m0 + cm;
        if (mg + 1 < l) v = *(const float4*)(tw + (size_t)jg * l + mg);
        else if (mg < l) { float2 t2 = tw[(size_t)jg * l + mg]; v.x = t2.x; v.y = t2.y; }
      }
      Bc[row][cm] = v.x;  Bn[row][cm] = v.y;
      Bc[row][cm+1] = v.z; Bn[row][cm+1] = v.w;
    }
    __syncthreads();
    #pragma unroll
    for (int j = 0; j < 16; j++) {
      float av[4], cr[4], ci[4];
      *(float4*)av = *(const float4*)&As[j][ty << 2];
      *(float4*)cr = *(const float4*)&Bc[j][tx << 2];
      *(float4*)ci = *(const float4*)&Bn[j][tx << 2];
      #pragma unroll
      for (int ii = 0; ii < 4; ii++)
        #pragma unroll
        for (int mm = 0; mm < 4; mm++) {
          are[ii][mm] = fmaf(av[ii],  cr[mm], are[ii][mm]);
          aim[ii][mm] = fmaf(av[ii], -ci[mm], aim[ii][mm]);
        }
    }
    __syncthreads();
  }
  #pragma unroll
  for (int ii = 0; ii < 4; ii++) {
    int i = i0 + (ty << 2) + ii;
    #pragma unroll
    for (int mm = 0; mm < 4; mm++) {
      int m = m0 + (tx << 2) + mm;
      if (m < l) dst[((size_t)b * CKD + i) * l + m] = make_float2(are[ii][mm], aim[ii][mm]);
    }
  }
}

// sum P partial spectra (scratch) into compact Dall/Sall slots
__global__ void reduce_k(float4* __restrict__ dD, float4* __restrict__ dS,
                         const float4* __restrict__ pD, const float4* __restrict__ pS,
                         int cnt4, int P) {
  int idx = blockIdx.x * blockDim.x + threadIdx.x;
  if (idx >= 2 * cnt4) return;
  const float4* src = (idx < cnt4) ? pD : pS;
  float4* dst = (idx < cnt4) ? dD : dS;
  int e = (idx < cnt4) ? idx : idx - cnt4;
  float4 a = src[e];
  for (int p = 1; p < P; p++) {
    float4 v = src[(size_t)p * cnt4 + e];
    a.x += v.x; a.y += v.y; a.z += v.z; a.w += v.w;
  }
  dst[e] = a;
}

// ONE launch for all levels: Uf[b,m,o] = sum_i Df[b,i,m]*WA + Sf[b,i,m]*WB ; Vf = Df*WC
// block 256 = (128 m-lanes x 2 o); grid (64 o-pairs, 52 quads: quad = lev*4 + bquad)
__global__ void mix_all_k(const float2* __restrict__ Dall, const float2* __restrict__ Sall,
                          const float* __restrict__ Ar, const float* __restrict__ Ai,
                          const float* __restrict__ Br, const float* __restrict__ Bi,
                          const float* __restrict__ Cr, const float* __restrict__ Ci,
                          float2* __restrict__ Uall, float2* __restrict__ Vall, MixTab mt) {
  int m = threadIdx.x & (CKD - 1);
  int oh = threadIdx.x >> 7;
  int o = (blockIdx.x << 1) + oh;
  int qy = blockIdx.y;
  int lev = qy >> 2;
  int b0 = (qy & 3) << 2;
  int l = mt.l[lev];
  if (m >= l) return;
  const float2* __restrict__ D = Dall + mt.off[lev];
  const float2* __restrict__ S = Sall + mt.off[lev];
  float2* __restrict__ U = Uall + mt.off[lev];
  float2* __restrict__ V = Vall + mt.off[lev];
  float ur[4] = {0.f,0.f,0.f,0.f}, ui[4] = {0.f,0.f,0.f,0.f};
  float vr[4] = {0.f,0.f,0.f,0.f}, vi[4] = {0.f,0.f,0.f,0.f};
  for (int i = 0; i < CKD; i++) {
    size_t wb = ((size_t)i * CKD + o) * AL + m;
    float ar = Ar[wb], ai = Ai[wb];
    float br = Br[wb], bi = Bi[wb];
    float cr = Cr[wb], ci = Ci[wb];
    #pragma unroll
    for (int q = 0; q < 4; q++) {
      size_t sb = ((size_t)(b0 + q) * CKD + i) * l + m;
      float2 d = D[sb];
      float2 s = S[sb];
      ur[q] += d.x*ar - d.y*ai + s.x*br - s.y*bi;
      ui[q] += d.x*ai + d.y*ar + s.x*bi + s.y*br;
      vr[q] += d.x*cr - d.y*ci;
      vi[q] += d.x*ci + d.y*cr;
    }
  }
  #pragma unroll
  for (int q = 0; q < 4; q++) {
    size_t ob = ((size_t)(b0 + q) * l + m) * CKD + o;
    U[ob] = make_float2(ur[q], ui[q]);
    V[ob] = make_float2(vr[q], vi[q]);
  }
}

// ---- tiled inverse DFT ----
// y[b,j,o] = (2*sum_{m=0..l-1}(Gr*cos - Gi*sin) - G0.re - nyq*(-1)^j*G[l-1].re)/n
__global__ void inv_dft_t(const float2* __restrict__ Uf, const float2* __restrict__ Vf,
                          float* __restrict__ ud, float* __restrict__ us,
                          const float2* __restrict__ twT, int n, int l, int nyq) {
  __shared__ float Gr[16][64];
  __shared__ float Gi[16][64];
  __shared__ float2 Ts[16][64];
  int z = blockIdx.z;
  const float2* __restrict__ G = (z ? Vf : Uf);
  float* __restrict__ out = (z ? us : ud);
  int j0 = blockIdx.x << 6;
  int by = blockIdx.y;
  int ot = by & 1, b = by >> 1;
  int o0 = ot << 6;
  int tid = threadIdx.x;
  int tx = tid & 15, ty = tid >> 4;
  float acc[4][4];
  #pragma unroll
  for (int a = 0; a < 4; a++)
    #pragma unroll
    for (int d = 0; d < 4; d++) acc[a][d] = 0.f;

  for (int m0 = 0; m0 < l; m0 += 16) {
    #pragma unroll
    for (int it2 = 0; it2 < 2; it2++) { // stage G into re/im planes
      int idx = tid + (it2 << 8);
      int row = idx >> 5;
      int co = (idx & 31) << 1;
      float4 v = make_float4(0.f,0.f,0.f,0.f);
      if (m0 + row < l)
        v = *(const float4*)(G + ((size_t)b * l + m0 + row) * CKD + o0 + co);
      Gr[row][co] = v.x;   Gi[row][co] = v.y;
      Gr[row][co+1] = v.z; Gi[row][co+1] = v.w;
    }
    #pragma unroll
    for (int it2 = 0; it2 < 2; it2++) { // stage twT tile
      int idx = tid + (it2 << 8);
      int row = idx >> 5;
      int cj = (idx & 31) << 1;
      float4 v = make_float4(0.f,0.f,0.f,0.f);
      if (m0 + row < l) {
        int jg = j0 + cj;
        if (jg + 1 < n) v = *(const float4*)(twT + (size_t)(m0 + row) * n + jg);
        else if (jg < n) { float2 t2 = twT[(size_t)(m0 + row) * n + jg]; v.x = t2.x; v.y = t2.y; }
      }
      *(float4*)&Ts[row][cj] = v;
    }
    __syncthreads();
    #pragma unroll
    for (int mm = 0; mm < 16; mm++) {
      float gr[4], gi[4];
      float2 cs[4];
      *(float4*)gr = *(const float4*)&Gr[mm][tx << 2];
      *(float4*)gi = *(const float4*)&Gi[mm][tx << 2];
      *(float4*)&cs[0] = *(const float4*)&Ts[mm][ty << 2];
      *(float4*)&cs[2] = *(const float4*)&Ts[mm][(ty << 2) + 2];
      #pragma unroll
      for (int jj = 0; jj < 4; jj++)
        #pragma unroll
        for (int oo = 0; oo < 4; oo++) {
          acc[jj][oo] = fmaf(gr[oo],  cs[jj].x, acc[jj][oo]);
          acc[jj][oo] = fmaf(gi[oo], -cs[jj].y, acc[jj][oo]);
        }
    }
    __syncthreads();
  }
  float invn = 1.f / (float)n;
  float g0[4], gn[4];
  #pragma unroll
  for (int oo = 0; oo < 4; oo++) {
    int o = o0 + (tx << 2) + oo;
    g0[oo] = G[((size_t)b * l) * CKD + o].x;
    gn[oo] = nyq ? G[((size_t)b * l + (l - 1)) * CKD + o].x : 0.f;
  }
  #pragma unroll
  for (int jj = 0; jj < 4; jj++) {
    int j = j0 + (ty << 2) + jj;
    if (j < n) {
      float sgn = (j & 1) ? -1.f : 1.f;
      float4 y;
      float* yp = &y.x;
      #pragma unroll
      for (int oo = 0; oo < 4; oo++)
        yp[oo] = (2.f * acc[jj][oo] - g0[oo] - sgn * gn[oo]) * invn;
      *(float4*)(out + ((size_t)b * n + j) * CKD + o0 + (tx << 2)) = y;
    }
  }
}

// coarsest map: y = x @ T0_w^T + T0_b
__global__ void t0_k(const float* __restrict__ xin, const float* __restrict__ w,
                     const float* __restrict__ bv, float* __restrict__ xout) {
  int idx = blockIdx.x * blockDim.x + threadIdx.x;
  if (idx >= BB * CC * KK) return;
  int k = idx & 3;
  int bc = idx >> 2;
  float a = bv[k];
  #pragma unroll
  for (int kp = 0; kp < 4; kp++) a = fmaf(xin[bc*4 + kp], w[k*4 + kp], a);
  xout[idx] = a;
}

__global__ void recon_k(const float* __restrict__ xin, const float* __restrict__ usl,
                        const float* __restrict__ udl,
                        const float* __restrict__ rce, const float* __restrict__ rco,
                        float* __restrict__ xout, int nh) {
  int idx = blockIdx.x * blockDim.x + threadIdx.x;
  if (idx >= BB * nh * CC) return;
  int c = idx & (CC - 1);
  int t = idx / CC;
  int j = t % nh;
  int b = t / nh;
  size_t ib = (((size_t)b * nh + j) * CC + c) * KK;
  float4 xv = *(const float4*)(xin + ib);
  float4 uv = *(const float4*)(usl + ib);
  float4 dv = *(const float4*)(udl + ib);
  float xx[8] = {xv.x+uv.x, xv.y+uv.y, xv.z+uv.z, xv.w+uv.w, dv.x, dv.y, dv.z, dv.w};
  float ev[4] = {0.f,0.f,0.f,0.f}, ov[4] = {0.f,0.f,0.f,0.f};
  #pragma unroll
  for (int p = 0; p < 8; p++) {
    float v = xx[p];
    #pragma unroll
    for (int k = 0; k < 4; k++) {
      ev[k] = fmaf(v, rce[p*4+k], ev[k]);
      ov[k] = fmaf(v, rco[p*4+k], ov[k]);
    }
  }
  size_t ob = (((size_t)b * (2*nh) + 2*j) * CC + c) * KK;
  *(float4*)(xout + ob) = make_float4(ev[0], ev[1], ev[2], ev[3]);
  *(float4*)(xout + ob + CC*KK) = make_float4(ov[0], ov[1], ov[2], ov[3]);
}

extern "C" void kernel_launch(void* const* d_in, const int* in_sizes, int n_in,
                              void* d_out, int out_size, void* d_ws, size_t ws_size,
                              hipStream_t stream) {
  const float* x   = (const float*)d_in[0];
  const float* wAr = (const float*)d_in[1];
  const float* wAi = (const float*)d_in[2];
  const float* wBr = (const float*)d_in[3];
  const float* wBi = (const float*)d_in[4];
  const float* wCr = (const float*)d_in[5];
  const float* wCi = (const float*)d_in[6];
  const float *ecs, *ecd, *rce, *rco, *t0w, *t0b;
  if (in_sizes[7] == 16) {
    t0w = (const float*)d_in[7];  t0b = (const float*)d_in[8];
    ecs = (const float*)d_in[9];  ecd = (const float*)d_in[10];
    rce = (const float*)d_in[11]; rco = (const float*)d_in[12];
  } else {
    ecs = (const float*)d_in[7];  ecd = (const float*)d_in[8];
    rce = (const float*)d_in[9];  rco = (const float*)d_in[10];
    t0w = (const float*)d_in[11]; t0b = (const float*)d_in[12];
  }

  int nh[NLEV], lv[NLEV];
  size_t twoff[NLEV], spoff[NLEV];   // spoff in float2 units within Dall/Sall/Uall/Vall
  size_t tacc = 0, spacc = 0;
  for (int q = 0; q < NLEV; q++) {
    nh[q] = NN >> (q + 1);
    int li = nh[q] / 2 + 1;
    lv[q] = li < AL ? li : AL;
    twoff[q] = tacc; tacc += (size_t)nh[q] * lv[q];
    spoff[q] = spacc; spacc += (size_t)BB * CKD * lv[q];
  }

  float* ws = (float*)d_ws;
  const size_t XS = (size_t)BB * (NN/2) * CKD;     // 8,388,608 floats
  float*  xb0  = ws;                               // XS floats
  float*  xb1  = xb0 + XS;                         // XS/2 floats (recon q=1 spills into Dall: dead then)
  float2* Dall = (float2*)(xb1 + XS / 2);          // spacc float2
  float2* Sall = Dall + spacc;
  float2* Uall = Sall + spacc;                     // also fwd partial scratch (dead until mix)
  float2* Vall = Uall + spacc;
  float*  udT  = (float*)(Vall + spacc);           // XS floats (also stages d per level)
  float*  usT  = udT + XS;                         // XS floats
  float2* tw   = (float2*)(usT + XS);
  float2* twT  = tw + tacc;
  float2* scrD = Uall;                             // fwd partials: up to PMAX * 262144 float2
  float2* scrS = Uall + (size_t)PMAX * BB * CKD * AL;

  LevTab lt;
  for (int q = 0; q < NLEV; q++) { lt.off[q] = (int)twoff[q]; lt.n[q] = nh[q]; lt.l[q] = lv[q]; }
  lt.total = (int)tacc;
  twiddle_fill_k<<<dim3((unsigned)((tacc + 255) / 256)), 256, 0, stream>>>(tw, twT, lt);

  // ---------- decompose + forward DFT (all levels) ----------
  const float* cur = x;
  float* nxt = xb0;
  for (int q = 0; q < NLEV; q++) {
    int n2 = nh[q], l = lv[q];
    float* dtmp = udT;                 // transient d staging
    int tot = BB * n2 * CC;
    decompose_k<<<dim3((tot + 255) / 256), 256, 0, stream>>>(cur, nxt, dtmp, ecs, ecd, n2);

    int P = n2 / 128; if (P < 1) P = 1; if (P > PMAX) P = PMAX;
    int chunk = (((n2 + P - 1) / P) + 15) & ~15;
    float2* Dp = (P > 1) ? scrD : (Dall + spoff[q]);
    float2* Sp = (P > 1) ? scrS : (Sall + spoff[q]);
    fwd_dft_t<<<dim3((l + 63) / 64, BB * 2, 2 * P), 256, 0, stream>>>(dtmp, nxt, Dp, Sp,
                                                                      tw + twoff[q], n2, l,
                                                                      P, chunk);
    if (P > 1) {
      int cnt4 = (BB * CKD * l) / 2;   // float4 per partial
      reduce_k<<<dim3((2 * cnt4 + 255) / 256), 256, 0, stream>>>(
          (float4*)(Dall + spoff[q]), (float4*)(Sall + spoff[q]),
          (const float4*)scrD, (const float4*)scrS, cnt4, P);
    }
    cur = nxt;
    nxt = (nxt == xb0) ? xb1 : xb0;
  }

  // ---------- one batched mode-mix over all levels ----------
  MixTab mt;
  for (int q = 0; q < NLEV; q++) { mt.off[q] = (long long)spoff[q]; mt.l[q] = lv[q]; }
  mix_all_k<<<dim3(CKD / 2, NLEV * BB / 4), 256, 0, stream>>>(Dall, Sall,
                                                              wAr, wAi, wBr, wBi, wCr, wCi,
                                                              Uall, Vall, mt);

  // ---------- coarsest linear map ----------
  // cur holds s12 (in xb0 after 13 alternations); write t0 out to the other buffer
  float* t0out = (cur == xb0) ? xb1 : xb0;
  t0_k<<<dim3((BB * CC * KK + 255) / 256), 256, 0, stream>>>(cur, t0w, t0b, t0out);

  // ---------- reconstruct (inverse DFT deferred per level) ----------
  const float* rcur = t0out;
  float* rnxt = (t0out == xb0) ? xb1 : xb0;
  for (int q = NLEV - 1; q >= 0; q--) {
    int n2 = nh[q], l = lv[q];
    int nyq = (((n2 & 1) == 0) && (l == n2 / 2 + 1)) ? 1 : 0;
    inv_dft_t<<<dim3((n2 + 63) / 64, BB * 2, 2), 256, 0, stream>>>(
        Uall + spoff[q], Vall + spoff[q], udT, usT, twT + twoff[q], n2, l, nyq);
    float* outp = (q == 0) ? (float*)d_out : rnxt;
    int tot = BB * n2 * CC;
    recon_k<<<dim3((tot + 255) / 256), 256, 0, stream>>>(rcur, usT, udT,
                                                         rce, rco, outp, n2);
    rcur = outp;
    rnxt = (rnxt == xb0) ? xb1 : xb0;
  }
}